// Round 8
// baseline (239.664 us; speedup 1.0000x reference)
//
#include <hip/hip_runtime.h>

// Cost-volume / correlation layer, fp32.
// out[b, dy*9+dx, h, w] = (1/C) * sum_c first[b,c,h,w] * second[b,c,h+dy-4,w+dx-4]
// (zero outside bounds).  B=8, C=128, H=W=128, search_range=4 -> 81 offsets.
//
// Round-11.  Model (fits R7/R9/R10): per channel per CU, VALU issue (~780cy/
// SIMD) and LDS service (~864cy/CU) run SERIALIZED because the barrier
// phase-locks all waves (ds-burst then FMA-burst, aligned).  R9 showed barrier
// count doesn't matter; R10 showed full-vmcnt drains and compiler VMEM in the
// loop are poison.  This round keeps R7's proven counted-vmcnt DMA skeleton
// and desynchronizes the pipes WITHIN each wave: after barrier k (publishing
// buf k+1), issue ds_reads for channel k+1 into regset B, then run channel
// k's FMAs from regset A -> each wave's LDS reads execute under its own FMA
// stream.  Also: 4-float zero pad per buffer; edge threads redirect their
// a0/a2 reads at it (loop-invariant) -> no per-channel cndmask zeroing.
// Safety: all loop VMEM is global_load_lds (deterministic FIFO, vmcnt(1)
// counted); lgkmcnt(0) before every barrier => no ds_read outstanding when
// any wave passes a barrier => DMA overwrite of buf k-2 provably race-free.

constexpr int B = 8, C = 128, H = 128, W = 128;
constexpr int RNG = 4, MO = 9;        // search range, max_offset
constexpr int RW  = 4;                // pixels per thread along w
constexpr int TH  = 2;                // h rows per block
constexpr int HWc = H * W;            // 16384
constexpr int SROWS = TH + 2 * RNG;   // 10 second rows
constexpr int SLABR = TH + SROWS;     // 12 rows (2 first + 10 second)
constexpr int SLAB  = SLABR * W;      // 1536 floats
constexpr int ZOFF  = SLAB;           // zero pad at end of each buffer
constexpr int SLABP = SLAB + 4;       // 1540 floats per buffer (6160 B, 16B-aligned)
constexpr int NBUF  = 4;

typedef float f32x4 __attribute__((ext_vector_type(4)));

__global__ __launch_bounds__(576)
__attribute__((amdgpu_waves_per_eu(5, 8)))   // VGPR <= 102: both blocks stay resident
void corr_kernel(const float* __restrict__ first,
                 const float* __restrict__ second,
                 float* __restrict__ out)
{
    const int tx = threadIdx.x;           // 0..31
    const int hy = threadIdx.y;           // 0..1
    const int dz = threadIdx.z;           // 0..8  (wave id == dz)
    const int h0 = blockIdx.x * TH;       // 0..126 (even)
    const int b  = blockIdx.y;
    const int w0 = tx * RW;               // 0..124
    const int lane = tx + 32 * hy;        // 0..63

    __shared__ __align__(16) float slab[NBUF][SLABP];   // ~24.1 KiB

    // zero pads, before the first barrier
    if (dz == 0 && hy == 0 && tx < NBUF * 4)
        slab[tx >> 2][ZOFF + (tx & 3)] = 0.0f;

    // staging roles (1 DMA per wave per channel):
    // wave 0: first rows (h0,h0+1) -> slab rows 0..1
    // waves 1..5: second row-pair q=dz-1: rows (h0-4+2q, h0-4+2q+1) -> rows
    //   2+2q..3+2q.  Pairs even-aligned => fully-valid or fully-invalid;
    //   invalid pairs clamp-staged (finite, never read).
    const float* gsrc = nullptr;
    int ldsoff = 0;
    if (dz == 0) {
        gsrc  = first + (size_t)b * C * HWc + h0 * W + lane * 4;
        ldsoff = 0;
    } else if (dz <= 5) {
        const int q  = dz - 1;
        const int r0 = h0 - RNG + 2 * q;                  // even, [-4,130]
        const int cs = r0 < 0 ? 0 : (r0 > H - 2 ? H - 2 : r0);
        gsrc  = second + (size_t)b * C * HWc + cs * W + lane * 4;
        ldsoff = (TH + 2 * q) * W;
    }
    const bool do_stage = (dz <= 5);

    // compute-side constants (all loop-invariant, incl. edge redirects)
    const int  srow   = h0 + hy + dz - RNG;
    const bool rvalid = (srow >= 0) && (srow < H);
    const int sbase = (TH + hy + dz) * W;               // slab row 2+hy+dz
    const int fbase = hy * W + w0;
    const int aoff1 = sbase + w0;
    const int aoff0 = (tx == 0)  ? ZOFF : (aoff1 - 4);  // edge -> zero pad
    const int aoff2 = (tx == 31) ? ZOFF : (aoff1 + 4);  // edge -> zero pad

    float acc[MO][RW];
#pragma unroll
    for (int i = 0; i < MO; ++i)
#pragma unroll
        for (int p = 0; p < RW; ++p) acc[i][p] = 0.0f;

#define STAGE(k)                                                            \
    if (do_stage) {                                                         \
        __builtin_amdgcn_global_load_lds(                                   \
            (const __attribute__((address_space(1))) void*)                 \
                (gsrc + (size_t)(k) * HWc),                                 \
            (__attribute__((address_space(3))) void*)                       \
                (&slab[(k) & (NBUF - 1)][ldsoff]),                          \
            16, 0, 0);                                                      \
    }

#define LDSREAD(SET, k)                                                     \
    {                                                                       \
        const float* sb = slab[(k) & (NBUF - 1)];                           \
        f##SET  = *(const f32x4*)(sb + fbase);                              \
        a0##SET = *(const f32x4*)(sb + aoff0);                              \
        a1##SET = *(const f32x4*)(sb + aoff1);                              \
        a2##SET = *(const f32x4*)(sb + aoff2);                              \
    }

#define COMPUTE(SET)                                                        \
    {                                                                       \
        const float s[12]  = {a0##SET.x, a0##SET.y, a0##SET.z, a0##SET.w,   \
                              a1##SET.x, a1##SET.y, a1##SET.z, a1##SET.w,   \
                              a2##SET.x, a2##SET.y, a2##SET.z, a2##SET.w};  \
        const float fvv[RW] = {f##SET.x, f##SET.y, f##SET.z, f##SET.w};     \
        _Pragma("unroll")                                                   \
        for (int dx = 0; dx < MO; ++dx)                                     \
            _Pragma("unroll")                                               \
            for (int p = 0; p < RW; ++p)                                    \
                acc[dx][p] += fvv[p] * s[p + dx];                           \
    }

// wait for stage(k+1) (1 left in FIFO after issuing stage(k+2)), drain own
// ds_reads, then rendezvous.  "memory" clobbers fence compiler memory ops.
#define SYNC1                                                               \
    asm volatile("s_waitcnt vmcnt(1) lgkmcnt(0)" ::: "memory");             \
    __builtin_amdgcn_sched_barrier(0);                                      \
    __builtin_amdgcn_s_barrier();

#define SYNC0                                                               \
    asm volatile("s_waitcnt vmcnt(0) lgkmcnt(0)" ::: "memory");             \
    __builtin_amdgcn_sched_barrier(0);                                      \
    __builtin_amdgcn_s_barrier();

#define BODY(k, CUR, NXT)                                                   \
    {                                                                       \
        STAGE((k) + 2)                                                      \
        SYNC1                           /* buf k+1 published */             \
        LDSREAD(NXT, (k) + 1)          /* reads overlap COMPUTE below */    \
        COMPUTE(CUR)                   /* channel k */                      \
    }

    f32x4 fA, a0A, a1A, a2A, fB, a0B, a1B, a2B;

    // prologue: FIFO [stage0, stage1]; wait vmcnt(1) -> buf0 ready
    STAGE(0)
    STAGE(1)
    SYNC1
    LDSREAD(A, 0)

    for (int k = 0; k < C - 4; k += 2) {   // k = 0..122 -> bodies 0..123
        BODY(k,     A, B)
        BODY(k + 1, B, A)
    }
    BODY(C - 4, A, B)                      // 124: stages 126
    BODY(C - 3, B, A)                      // 125: stages 127
    // 126: FIFO [stage127]; no more staging
    SYNC0
    LDSREAD(B, C - 1)
    COMPUTE(A)                             // channel 126
    COMPUTE(B)                             // channel 127 (lgkm via data-dep)

#undef BODY
#undef SYNC0
#undef SYNC1
#undef COMPUTE
#undef LDSREAD
#undef STAGE

    // invalid srow => result must be 0 (acc holds finite garbage; *0 is safe)
    const float inv = rvalid ? (1.0f / (float)C) : 0.0f;
    float* obase = out + ((size_t)b * (MO * MO) + (size_t)dz * MO) * HWc
                       + (size_t)(h0 + hy) * W + w0;
#pragma unroll
    for (int dx = 0; dx < MO; ++dx) {
        f32x4 v = {acc[dx][0] * inv, acc[dx][1] * inv,
                   acc[dx][2] * inv, acc[dx][3] * inv};
        *(f32x4*)(obase + (size_t)dx * HWc) = v;
    }
}

extern "C" void kernel_launch(void* const* d_in, const int* in_sizes, int n_in,
                              void* d_out, int out_size, void* d_ws, size_t ws_size,
                              hipStream_t stream) {
    const float* first  = (const float*)d_in[0];
    const float* second = (const float*)d_in[1];
    float* out = (float*)d_out;

    dim3 grid(H / TH, B);       // (64, 8) = 512 blocks = 2 per CU
    dim3 block(32, TH, MO);     // 576 threads = 9 waves, wave id == dy
    corr_kernel<<<grid, block, 0, stream>>>(first, second, out);
}

// Round 9
// 194.569 us; speedup vs baseline: 1.2318x; 1.2318x over previous
//
#include <hip/hip_runtime.h>

// Cost-volume / correlation layer, fp32.
// out[b, dy*9+dx, h, w] = (1/C) * sum_c first[b,c,h,w] * second[b,c,h+dy-4,w+dx-4]
// (zero outside bounds).  B=8, C=128, H=W=128, search_range=4 -> 81 offsets.
//
// Round-12: BARRIER-FREE.  Evidence chain: R9 (barrier count irrelevant),
// R10 (DS count irrelevant), R11 (in-wave regset rotation: spills+conflicts).
// Remaining consistent theory: the block barrier phase-locks all 18 waves
// (ds-burst || idle VALU, then FMA-burst || idle LDS) -> pipes serialized.
// Fix: no cross-wave sharing at all.  Each wave stages ITS OWN 4 rows
// (2 first + its 2 second rows) into private LDS buffers, 2 global_load_lds
// per channel using PER-LANE global source addresses (lane>=32 -> next row,
// per-row clamp exact).  Per-wave in-order FIFO of only its own DMAs ->
// counted vmcnt(4) is exact; no barriers anywhere; waves self-stagger so
// LDS + VALU pipes overlap across the 18-wave ensemble.
// Race-free by construction: a wave reads only buffers it wrote; its FMAs
// (data-dep on ds_reads) retire before it issues the overwriting DMA; asm
// "memory" clobber + sched_barrier(0) pin ds_reads below the vmcnt wait.
// Cost: LDS-DMA writes 12->36 KB/channel/CU, ~3x L1/L2 re-reads (unique
// HBM data unchanged).  Bound: max(LDS ~1150cy, VALU ~550cy) vs 1556 now.

constexpr int B = 8, C = 128, H = 128, W = 128;
constexpr int RNG = 4, MO = 9;        // search range, max_offset
constexpr int RW  = 4;                // pixels per thread along w
constexpr int TH  = 2;                // h rows per block
constexpr int HWc = H * W;            // 16384
constexpr int BROWS = 4;              // rows per wave-buffer: f0,f1,s0,s1
constexpr int BUFW  = BROWS * W;      // 512 floats = 2 KiB
constexpr int NBUF  = 4;              // per-wave channel buffers

typedef float f32x4 __attribute__((ext_vector_type(4)));

__global__ __launch_bounds__(576)
__attribute__((amdgpu_waves_per_eu(2, 5)))
void corr_kernel(const float* __restrict__ first,
                 const float* __restrict__ second,
                 float* __restrict__ out)
{
    const int tx = threadIdx.x;           // 0..31
    const int hy = threadIdx.y;           // 0..1
    const int dz = threadIdx.z;           // 0..8  (wave id == dz == dy)
    const int h0 = blockIdx.x * TH;       // 0..126 (even)
    const int b  = blockIdx.y;
    const int w0 = tx * RW;               // 0..124
    const int lane = tx + 32 * hy;        // 0..63

    __shared__ __align__(16) float slab[MO][NBUF][BUFW];   // 72 KiB

    // ---- per-lane DMA sources (one wave stages its own 4 rows) ----
    // f-op : lane l -> first row h0 + (l>>5),          col (l&31)*4
    // s-op : lane l -> second row clamp(h0+dz-4+(l>>5)), col (l&31)*4
    // (global source of global_load_lds is per-lane; LDS dest is base+l*16)
    const int ls = lane >> 5;             // which row of the pair
    const int lc = (lane & 31) * 4;       // col offset in floats
    const float* gf = first + (size_t)b * C * HWc + (size_t)(h0 + ls) * W + lc;
    const int  sr  = h0 + dz - RNG + ls;  // may be out of [0,H)
    const int  src = sr < 0 ? 0 : (sr > H - 1 ? H - 1 : sr);   // per-row clamp
    const float* gs = second + (size_t)b * C * HWc + (size_t)src * W + lc;

    float* mybuf = &slab[dz][0][0];       // wave-private, wave-uniform base

    // compute-side constants (loop-invariant)
    const int  srow   = h0 + hy + dz - RNG;
    const bool rvalid = (srow >= 0) && (srow < H);
    const bool ledge  = (tx == 0);
    const bool redge  = (tx == 31);
    const int o_f  = hy * W + w0;                     // f row hy
    const int o_a1 = (2 + hy) * W + w0;               // s row 2+hy
    const int o_a0 = ledge ? o_a1 : (o_a1 - 4);       // in-buffer redirect
    const int o_a2 = redge ? o_a1 : (o_a1 + 4);       // (zeroed below)

    float acc[MO][RW];
#pragma unroll
    for (int i = 0; i < MO; ++i)
#pragma unroll
        for (int p = 0; p < RW; ++p) acc[i][p] = 0.0f;

#define STAGE(k)                                                            \
    {                                                                       \
        float* db = mybuf + ((k) & (NBUF - 1)) * BUFW;                      \
        __builtin_amdgcn_global_load_lds(                                   \
            (const __attribute__((address_space(1))) void*)                 \
                (gf + (size_t)(k) * HWc),                                   \
            (__attribute__((address_space(3))) void*)db, 16, 0, 0);         \
        __builtin_amdgcn_global_load_lds(                                   \
            (const __attribute__((address_space(1))) void*)                 \
                (gs + (size_t)(k) * HWc),                                   \
            (__attribute__((address_space(3))) void*)(db + 2 * W),          \
            16, 0, 0);                                                      \
    }

#define COMPUTE(k)                                                         \
    {                                                                       \
        const float* sb = mybuf + ((k) & (NBUF - 1)) * BUFW;                \
        f32x4 fv = *(const f32x4*)(sb + o_f);                               \
        f32x4 a0 = *(const f32x4*)(sb + o_a0);                              \
        f32x4 a1 = *(const f32x4*)(sb + o_a1);                              \
        f32x4 a2 = *(const f32x4*)(sb + o_a2);                              \
        if (ledge) a0 = (f32x4){0.f, 0.f, 0.f, 0.f};                        \
        if (redge) a2 = (f32x4){0.f, 0.f, 0.f, 0.f};                        \
        const float s[12]  = {a0.x, a0.y, a0.z, a0.w,                       \
                              a1.x, a1.y, a1.z, a1.w,                       \
                              a2.x, a2.y, a2.z, a2.w};                      \
        const float fvv[RW] = {fv.x, fv.y, fv.z, fv.w};                     \
        _Pragma("unroll")                                                   \
        for (int dx = 0; dx < MO; ++dx)                                     \
            _Pragma("unroll")                                               \
            for (int p = 0; p < RW; ++p)                                    \
                acc[dx][p] += fvv[p] * s[p + dx];                           \
    }

// wait until only N of this wave's own DMA ops remain in flight, then keep
// the compiler from hoisting the ds_reads above the wait.
#define VWAIT(N)                                                            \
    asm volatile("s_waitcnt vmcnt(" #N ")" ::: "memory");                   \
    __builtin_amdgcn_sched_barrier(0);

    // prologue: 3 channels in flight (6 ops)
    STAGE(0)
    STAGE(1)
    STAGE(2)

#pragma unroll 4
    for (int k = 0; k < C - 3; ++k) {     // k = 0..124
        VWAIT(4)                          // stage(k) landed; k+1,k+2 in flight
        STAGE(k + 3)
        COMPUTE(k)
    }
    VWAIT(4)  COMPUTE(C - 3)              // C-2, C-1 in flight
    VWAIT(2)  COMPUTE(C - 2)              // C-1 in flight
    VWAIT(0)  COMPUTE(C - 1)

#undef VWAIT
#undef COMPUTE
#undef STAGE

    // invalid srow => result must be 0 (acc holds finite garbage; *0 is safe)
    const float inv = rvalid ? (1.0f / (float)C) : 0.0f;
    float* obase = out + ((size_t)b * (MO * MO) + (size_t)dz * MO) * HWc
                       + (size_t)(h0 + hy) * W + w0;
#pragma unroll
    for (int dx = 0; dx < MO; ++dx) {
        f32x4 v = {acc[dx][0] * inv, acc[dx][1] * inv,
                   acc[dx][2] * inv, acc[dx][3] * inv};
        *(f32x4*)(obase + (size_t)dx * HWc) = v;
    }
}

extern "C" void kernel_launch(void* const* d_in, const int* in_sizes, int n_in,
                              void* d_out, int out_size, void* d_ws, size_t ws_size,
                              hipStream_t stream) {
    const float* first  = (const float*)d_in[0];
    const float* second = (const float*)d_in[1];
    float* out = (float*)d_out;

    dim3 grid(H / TH, B);       // (64, 8) = 512 blocks = 2 per CU
    dim3 block(32, TH, MO);     // 576 threads = 9 waves, wave id == dy
    corr_kernel<<<grid, block, 0, stream>>>(first, second, out);
}

// Round 10
// 181.089 us; speedup vs baseline: 1.3235x; 1.0744x over previous
//
#include <hip/hip_runtime.h>

// Cost-volume / correlation layer, fp32.
// out[b, dy*9+dx, h, w] = (1/C) * sum_c first[b,c,h,w] * second[b,c,h+dy-4,w+dx-4]
// (zero outside bounds).  B=8, C=128, H=W=128, search_range=4 -> 81 offsets.
//
// Round-13: R7 body UNCHANGED (83us anchor; counted-vmcnt DMA pipeline).
// Sync-structure theories exhausted (R9: barrier count, R10: DS count,
// R11: regset rotation, R12: barrier-free -- none beat R7).  Remaining
// evidence: FETCH=193MB vs 128MB unique (second rows shared 8/10 with
// h0+-2 neighbor blocks, but default dispatch round-robins adjacent h0
// across the 8 non-coherent XCD L2s), and R7/R9/R12 all sit at 2.7-2.9TB/s
// effective HBM.  This round: XCD-aware bijective block remap (T1) so each
// XCD owns 2 batches x 32 contiguous h0-pairs.  Per-XCD per-channel working
// set ~74KB (L2 tolerates ~55 channels of inter-block drift) -> second
// fetch ~129MB -> ~74MB.  Single variable; kernel body byte-identical.

constexpr int B = 8, C = 128, H = 128, W = 128;
constexpr int RNG = 4, MO = 9;        // search range, max_offset
constexpr int RW  = 4;                // pixels per thread along w
constexpr int TH  = 2;                // h rows per block
constexpr int HWc = H * W;            // 16384
constexpr int SROWS = TH + 2 * RNG;   // 10 second rows per block
constexpr int SLAB  = (TH + SROWS) * W;   // 12*128 = 1536 floats = 6 KiB
constexpr int NBUF  = 4;              // distance-2 pipeline => 4 buffers

typedef float f32x4 __attribute__((ext_vector_type(4)));

__global__ __launch_bounds__(576)
__attribute__((amdgpu_waves_per_eu(2, 5)))
void corr_kernel(const float* __restrict__ first,
                 const float* __restrict__ second,
                 float* __restrict__ out)
{
    const int tx = threadIdx.x;           // 0..31
    const int hy = threadIdx.y;           // 0..1
    const int dz = threadIdx.z;           // 0..8  (== wave id)
    const int w0 = tx * RW;               // 0..124
    const int lane = tx + 32 * hy;        // 0..63

    // ---- XCD-aware bijective remap (hardware: XCD = linear_wgid % 8) ----
    // XCD c owns b in {2*(c&3), 2*(c&3)+1}, h0-pair index in
    // [32*(c>>2), 32*(c>>2)+32).  512 blocks = 8 XCD x 2 b x 32 h0i.
    const int ell = blockIdx.x + gridDim.x * blockIdx.y;   // linear wg id
    const int xcd = ell & 7;
    const int sid = ell >> 3;                              // 0..63
    const int b   = 2 * (xcd & 3) + (sid >> 5);
    const int h0  = (32 * (xcd >> 2) + (sid & 31)) * TH;   // 0..126, even

    __shared__ __align__(16) float slab[NBUF][SLAB];

    // ---- staging roles (wave-uniform: one 1KiB DMA per wave per channel) ----
    // wave 0: first rows (h0, h0+1) -> slab rows 0..1
    // waves 1..5: second row-pair p = dz-1: rows (h0-4+2p, h0-4+2p+1)
    //             -> slab rows 2+2p .. 3+2p.  Pairs are even-aligned, so each
    //             pair is fully-valid or fully-invalid; invalid pairs are
    //             clamp-staged (finite data, never read).
    const float* gsrc = nullptr;
    int ldsoff = 0;
    if (dz == 0) {
        gsrc  = first + (size_t)b * C * HWc + h0 * W + lane * 4;
        ldsoff = 0;
    } else if (dz <= 5) {
        const int p  = dz - 1;
        const int r0 = h0 - RNG + 2 * p;                  // even, in [-4,130]
        const int cs = r0 < 0 ? 0 : (r0 > H - 2 ? H - 2 : r0);
        gsrc  = second + (size_t)b * C * HWc + cs * W + lane * 4;
        ldsoff = (TH + 2 * p) * W;
    }
    const bool do_stage = (dz <= 5);

    // ---- compute-side constants ----
    const int  srow   = h0 + hy + dz - RNG;
    const bool rvalid = (srow >= 0) && (srow < H);
    const bool ledge  = (tx == 0);
    const bool redge  = (tx == 31);
    const int off0  = ledge ? 0       : (w0 - 4);   // in-row, 16B aligned
    const int off2  = redge ? (W - 8) : (w0 + 4);
    const int fbase = hy * W + w0;
    const int sbase = (TH + hy + dz) * W;           // slab row 2+hy+dz

    float acc[MO][RW];
#pragma unroll
    for (int i = 0; i < MO; ++i)
#pragma unroll
        for (int p = 0; p < RW; ++p) acc[i][p] = 0.0f;

#define STAGE(k)                                                            \
    if (do_stage) {                                                         \
        __builtin_amdgcn_global_load_lds(                                   \
            (const __attribute__((address_space(1))) void*)                 \
                (gsrc + (size_t)(k) * HWc),                                 \
            (__attribute__((address_space(3))) void*)                       \
                (&slab[(k) & (NBUF - 1)][ldsoff]),                          \
            16, 0, 0);                                                      \
    }

    STAGE(0)
    STAGE(1)

    for (int k = 0; k < C; ++k) {
        if (k < C - 2) {
            STAGE(k + 2)                     // issue DMA for k+2 (buf (k+2)&3)
            asm volatile("s_waitcnt vmcnt(2)" ::: "memory");   // stage(k) done
        } else if (k == C - 2) {
            asm volatile("s_waitcnt vmcnt(1)" ::: "memory");
        } else {
            asm volatile("s_waitcnt vmcnt(0)" ::: "memory");
        }
        __builtin_amdgcn_s_barrier();        // publish buf k to all waves

        const float* sb = slab[k & (NBUF - 1)];
        f32x4 fv = *(const f32x4*)(sb + fbase);
        f32x4 a0 = *(const f32x4*)(sb + sbase + off0);
        f32x4 a1 = *(const f32x4*)(sb + sbase + w0);
        f32x4 a2 = *(const f32x4*)(sb + sbase + off2);
        if (ledge) a0 = (f32x4){0.f, 0.f, 0.f, 0.f};
        if (redge) a2 = (f32x4){0.f, 0.f, 0.f, 0.f};
        const float s[12] = {a0.x, a0.y, a0.z, a0.w,
                             a1.x, a1.y, a1.z, a1.w,
                             a2.x, a2.y, a2.z, a2.w};
        const float fvv[RW] = {fv.x, fv.y, fv.z, fv.w};
#pragma unroll
        for (int dx = 0; dx < MO; ++dx)
#pragma unroll
            for (int p = 0; p < RW; ++p)
                acc[dx][p] += fvv[p] * s[p + dx];

        // all ds_reads complete before we pass the next barrier (closes the
        // read-in-flight vs DMA-overwrite race); pin compiler ordering.
        asm volatile("s_waitcnt lgkmcnt(0)" ::: "memory");
        __builtin_amdgcn_sched_barrier(0);
    }
#undef STAGE

    // invalid srow => result must be 0 (acc holds finite garbage; *0 is safe)
    const float inv = rvalid ? (1.0f / (float)C) : 0.0f;
    float* obase = out + ((size_t)b * (MO * MO) + (size_t)dz * MO) * HWc
                       + (size_t)(h0 + hy) * W + w0;
#pragma unroll
    for (int dx = 0; dx < MO; ++dx) {
        f32x4 v = {acc[dx][0] * inv, acc[dx][1] * inv,
                   acc[dx][2] * inv, acc[dx][3] * inv};
        *(f32x4*)(obase + (size_t)dx * HWc) = v;
    }
}

extern "C" void kernel_launch(void* const* d_in, const int* in_sizes, int n_in,
                              void* d_out, int out_size, void* d_ws, size_t ws_size,
                              hipStream_t stream) {
    const float* first  = (const float*)d_in[0];
    const float* second = (const float*)d_in[1];
    float* out = (float*)d_out;

    dim3 grid(H / TH, B);       // (64, 8) = 512 blocks = exactly 2 per CU
    dim3 block(32, TH, MO);     // 576 threads = 9 waves, wave id == dy
    corr_kernel<<<grid, block, 0, stream>>>(first, second, out);
}